// Round 8
// baseline (101.295 us; speedup 1.0000x reference)
//
#include <hip/hip_runtime.h>
#include <hip/hip_bf16.h>
#include <math.h>

// Problem constants (from reference)
#define BB 32
#define CC 30
#define RR 196
#define DD 256
#define KK 20
#define GG 14            // sqrt(RR)
#define CONF_ 0.5f
#define IOU_THR_ 0.3f

constexpr int COORDS_OFF = 0;                // (B,C,K,4)
constexpr int PROBS_OFF  = BB * CC * KK * 4; // 76800
constexpr int KEEP_OFF   = PROBS_OFF + BB * CC * KK;  // 96000
constexpr int PRES_OFF   = KEEP_OFF + BB * CC * KK;   // 115200

__device__ __forceinline__ float dot4(float4 a, float4 b) {
    return a.x * b.x + a.y * b.y + a.z * b.z + a.w * b.w;
}

// ---------------------------------------------------------------------------
// DIAGNOSTIC ROUND (R7): identical math/output to the passing R5 kernel, but
// phase 1 streams lf THREE times. Passes 0-1: loads + dots only, results kept
// alive via empty asm (no DCE, no side effects). Pass 2: real pass (reduce +
// LDS + presence write). Purpose: push dur_us above the harness's ~110 µs
// d_ws fill kernels so THIS kernel surfaces in the rocprof top-5 and we
// finally read its FETCH_SIZE / OccupancyPercent / VALUBusy. Four different
// streaming structures all landed at ~4 TB/s; this round identifies whether
// that is a read-path/L3 BW ceiling (then R5 is the roofline) or a fixable
// occupancy/consumption pathology.
// ---------------------------------------------------------------------------
__global__ __launch_bounds__(256, 4) void fused_bbox_diag3x(
    const float4* __restrict__ lf,        // (B*C*R) x 64 float4
    const float*  __restrict__ W_coords,  // 4 x 256
    const float*  __restrict__ b_coords,  // 4
    const float*  __restrict__ W_pres,    // 256
    const float*  __restrict__ b_pres,    // 1
    float* __restrict__ coords_out,
    float* __restrict__ probs_out,
    float* __restrict__ keep_out,
    float* __restrict__ presence_out)
{
    const int bc   = blockIdx.x;
    const int tid  = threadIdx.x;
    const int wv   = tid >> 6;
    const int lane = tid & 63;
    const int gr   = lane >> 4;   // row slot within granule (0..3)
    const int o    = lane & 15;   // sub-lane within row

    __shared__ float  s_logit[RR];
    __shared__ float4 s_box[RR];

    const float4* __restrict__ Wp4 = reinterpret_cast<const float4*>(W_pres);
    const float4* __restrict__ Wc4 = reinterpret_cast<const float4*>(W_coords);

    // All weights in registers, loaded once (L1-hit), loop-invariant.
    float4 wp[4], w0[4], w1[4], w2[4], w3[4];
    #pragma unroll
    for (int t = 0; t < 4; ++t) {
        wp[t] = Wp4[o + 16 * t];
        w0[t] = Wc4[      o + 16 * t];
        w1[t] = Wc4[ 64 + o + 16 * t];
        w2[t] = Wc4[128 + o + 16 * t];
        w3[t] = Wc4[192 + o + 16 * t];
    }
    const float bp  = b_pres[0];
    const float bc0 = b_coords[0], bc1 = b_coords[1];
    const float bc2 = b_coords[2], bc3 = b_coords[3];

    const size_t tile  = (size_t)bc * RR;
    const int    wbase = wv * 49;         // 4 waves x 49 rows = 196

    #pragma unroll 1
    for (int pass = 0; pass < 3; ++pass) {
        // ---- 12 granules of 4 rows ----
        #pragma unroll 1
        for (int j = 0; j < 12; ++j) {
            const int r = wbase + 4 * j + gr;
            const float4* __restrict__ rp = lf + (tile + r) * 64;

            float ap = 0.f, a0 = 0.f, a1 = 0.f, a2 = 0.f, a3 = 0.f;
            #pragma unroll
            for (int t = 0; t < 4; ++t) {
                const float4 x = rp[o + 16 * t];
                ap += dot4(x, wp[t]);
                a0 += dot4(x, w0[t]);
                a1 += dot4(x, w1[t]);
                a2 += dot4(x, w2[t]);
                a3 += dot4(x, w3[t]);
            }
            if (pass < 2) {
                // keep the loads+dots alive; no reduce, no writes
                asm volatile("" :: "v"(ap), "v"(a0), "v"(a1), "v"(a2), "v"(a3));
            } else {
                #pragma unroll
                for (int off = 1; off <= 8; off <<= 1) {
                    ap += __shfl_xor(ap, off);
                    a0 += __shfl_xor(a0, off);
                    a1 += __shfl_xor(a1, off);
                    a2 += __shfl_xor(a2, off);
                    a3 += __shfl_xor(a3, off);
                }
                if (o == 0) {
                    const float lg = ap + bp;
                    s_logit[r] = lg;
                    presence_out[tile + r] = lg;
                    const int   ix = r % GG, iy = r / GG;
                    const float cx = (ix + 0.5f) / (float)GG;
                    const float cy = (iy + 0.5f) / (float)GG;
                    s_box[r] = make_float4(a0 + bc0 + cx, a1 + bc1 + cy,
                                           a2 + bc2 + cx, a3 + bc3 + cy);
                }
            }
        }

        // ---- tail row wbase+48: lanes 0..15 ----
        if (gr == 0) {
            const int r = wbase + 48;
            const float4* __restrict__ rp = lf + (tile + r) * 64;
            float ap = 0.f, a0 = 0.f, a1 = 0.f, a2 = 0.f, a3 = 0.f;
            #pragma unroll
            for (int t = 0; t < 4; ++t) {
                const float4 x = rp[o + 16 * t];
                ap += dot4(x, wp[t]);
                a0 += dot4(x, w0[t]);
                a1 += dot4(x, w1[t]);
                a2 += dot4(x, w2[t]);
                a3 += dot4(x, w3[t]);
            }
            if (pass < 2) {
                asm volatile("" :: "v"(ap), "v"(a0), "v"(a1), "v"(a2), "v"(a3));
            } else {
                #pragma unroll
                for (int off = 1; off <= 8; off <<= 1) {
                    ap += __shfl_xor(ap, off);
                    a0 += __shfl_xor(a0, off);
                    a1 += __shfl_xor(a1, off);
                    a2 += __shfl_xor(a2, off);
                    a3 += __shfl_xor(a3, off);
                }
                if (o == 0) {
                    const float lg = ap + bp;
                    s_logit[r] = lg;
                    presence_out[tile + r] = lg;
                    const int   ix = r % GG, iy = r / GG;
                    const float cx = (ix + 0.5f) / (float)GG;
                    const float cy = (iy + 0.5f) / (float)GG;
                    s_box[r] = make_float4(a0 + bc0 + cx, a1 + bc1 + cy,
                                           a2 + bc2 + cx, a3 + bc3 + cy);
                }
            }
        }
    }

    __syncthreads();
    if (wv != 0) return;

    // ---- Phase 2 (wave 0): top-K argmax over LDS logits ----
    float v[4]; int id[4];
    #pragma unroll
    for (int t = 0; t < 4; ++t) {
        const int r = lane + 64 * t;
        id[t] = r;
        v[t]  = (r < RR) ? s_logit[r] : -1e30f;
    }

    float myv = -1e30f; int myi = 0;
    for (int k = 0; k < KK; ++k) {
        float bv = v[0]; int bi = id[0];
        #pragma unroll
        for (int t = 1; t < 4; ++t)
            if (v[t] > bv || (v[t] == bv && id[t] < bi)) { bv = v[t]; bi = id[t]; }
        #pragma unroll
        for (int off = 32; off; off >>= 1) {
            const float ov = __shfl_xor(bv, off);
            const int   oi = __shfl_xor(bi, off);
            if (ov > bv || (ov == bv && oi < bi)) { bv = ov; bi = oi; }
        }
        #pragma unroll
        for (int t = 0; t < 4; ++t)
            if (id[t] == bi) v[t] = -1e30f;
        if (lane == k) { myv = bv; myi = bi; }
    }

    // ---- box fetch + NMS ----
    float x1 = 0.f, y1 = 0.f, x2 = 0.f, y2 = 0.f, area = 0.f, prob = 0.f;
    int kp = 0;
    if (lane < KK) {
        const float4 b = s_box[myi];
        x1 = b.x; y1 = b.y; x2 = b.z; y2 = b.w;
        area = fmaxf(x2 - x1, 0.f) * fmaxf(y2 - y1, 0.f);
        prob = 1.f / (1.f + expf(-myv));
        kp   = (prob > CONF_) ? 1 : 0;
    }
    for (int i = 0; i < KK; ++i) {
        const int   ki  = __shfl(kp, i);
        const float bx1 = __shfl(x1, i), by1 = __shfl(y1, i);
        const float bx2 = __shfl(x2, i), by2 = __shfl(y2, i);
        const float ai  = __shfl(area, i);
        if (lane > i && lane < KK && ki) {
            const float xx1 = fmaxf(x1, bx1), yy1 = fmaxf(y1, by1);
            const float xx2 = fminf(x2, bx2), yy2 = fminf(y2, by2);
            const float inter = fmaxf(xx2 - xx1, 0.f) * fmaxf(yy2 - yy1, 0.f);
            const float uni   = area + ai - inter;
            const float iou   = inter / fmaxf(uni, 1e-9f);
            if (iou > IOU_THR_) kp = 0;
        }
    }

    // ---- outputs ----
    if (lane < KK) {
        const size_t obase = (size_t)bc * KK + lane;
        const float  kf    = kp ? 1.f : 0.f;
        coords_out[obase * 4 + 0] = x1 * kf;
        coords_out[obase * 4 + 1] = y1 * kf;
        coords_out[obase * 4 + 2] = x2 * kf;
        coords_out[obase * 4 + 3] = y2 * kf;
        probs_out[obase] = prob * kf;
        keep_out[obase]  = kf;
    }
}

extern "C" void kernel_launch(void* const* d_in, const int* in_sizes, int n_in,
                              void* d_out, int out_size, void* d_ws, size_t ws_size,
                              hipStream_t stream) {
    const float* lf       = (const float*)d_in[0];
    const float* W_coords = (const float*)d_in[1];
    const float* b_coords = (const float*)d_in[2];
    const float* W_pres   = (const float*)d_in[3];
    const float* b_pres   = (const float*)d_in[4];

    float* out          = (float*)d_out;
    float* coords_out   = out + COORDS_OFF;
    float* probs_out    = out + PROBS_OFF;
    float* keep_out     = out + KEEP_OFF;
    float* presence_out = out + PRES_OFF;

    // One block per (b,c); 960 blocks, fully independent (single launch).
    fused_bbox_diag3x<<<BB * CC, 256, 0, stream>>>(
        (const float4*)lf, W_coords, b_coords, W_pres, b_pres,
        coords_out, probs_out, keep_out, presence_out);
}

// Round 9
// 75.652 us; speedup vs baseline: 1.3390x; 1.3390x over previous
//
#include <hip/hip_runtime.h>
#include <hip/hip_bf16.h>
#include <math.h>

// Problem constants (from reference)
#define BB 32
#define CC 30
#define RR 196
#define DD 256
#define KK 20
#define GG 14            // sqrt(RR)
#define CONF_ 0.5f
#define IOU_THR_ 0.3f

constexpr int COORDS_OFF = 0;                // (B,C,K,4)
constexpr int PROBS_OFF  = BB * CC * KK * 4; // 76800
constexpr int KEEP_OFF   = PROBS_OFF + BB * CC * KK;  // 96000
constexpr int PRES_OFF   = KEEP_OFF + BB * CC * KK;   // 115200

__device__ __forceinline__ float dot4(float4 a, float4 b) {
    return a.x * b.x + a.y * b.y + a.z * b.z + a.w * b.w;
}

// ---------------------------------------------------------------------------
// R8: weights in LDS, data loads deep-pipelined.
// R7 diagnosis: VGPR=64 proved the compiler never register-pinned the 20
// weight float4s — it RELOADED them from global per granule. vmcnt is
// in-order, so each weight-load waitcnt drained the in-flight data loads ->
// one full memory latency per granule -> ~4 TB/s flat across R1-R6.
// Fix: weights live in LDS (ds_read -> lgkmcnt, a SEPARATE counter from
// vmcnt) so weight reads never drain the data-load queue; and the granule
// loop is 2-deep software-pipelined (issue granule j+1's 4 loads before
// computing granule j) so each wave holds ~8KB of data loads in flight
// continuously.
// Structure otherwise identical to the passing R5 kernel:
//   one block per (b,c), 4 waves x 49 rows, granule = 4 rows x 16 lanes,
//   phase-2 epilogue on wave 0 from LDS.
// ---------------------------------------------------------------------------
__global__ __launch_bounds__(256, 4) void fused_bbox_ldsw(
    const float4* __restrict__ lf,        // (B*C*R) x 64 float4
    const float*  __restrict__ W_coords,  // 4 x 256
    const float*  __restrict__ b_coords,  // 4
    const float*  __restrict__ W_pres,    // 256
    const float*  __restrict__ b_pres,    // 1
    float* __restrict__ coords_out,
    float* __restrict__ probs_out,
    float* __restrict__ keep_out,
    float* __restrict__ presence_out)
{
    const int bc   = blockIdx.x;
    const int tid  = threadIdx.x;
    const int wv   = tid >> 6;
    const int lane = tid & 63;
    const int gr   = lane >> 4;   // row slot within granule (0..3)
    const int o    = lane & 15;   // sub-lane within row

    __shared__ float4 s_w[320];   // [stream*64 + e]; stream 0 = pres, 1..4 = coords
    __shared__ float  s_logit[RR];
    __shared__ float4 s_box[RR];

    const float4* __restrict__ Wp4 = reinterpret_cast<const float4*>(W_pres);
    const float4* __restrict__ Wc4 = reinterpret_cast<const float4*>(W_coords);

    // cooperative weight staging: 320 float4s by 256 threads
    for (int i = tid; i < 320; i += 256) {
        const int s = i >> 6, e = i & 63;
        s_w[i] = (s == 0) ? Wp4[e] : Wc4[(s - 1) * 64 + e];
    }
    __syncthreads();

    const float bp  = b_pres[0];
    const float bc0 = b_coords[0], bc1 = b_coords[1];
    const float bc2 = b_coords[2], bc3 = b_coords[3];

    const size_t tile  = (size_t)bc * RR;
    const float4* __restrict__ tp = lf + tile * 64;
    const int    wbase = wv * 49;         // 4 waves x 49 rows = 196

    // data load: granule j -> rows wbase+4j+gr, taps o+16t
#define LOADG(X, j)                                                       \
    {                                                                     \
        const float4* __restrict__ _p = tp + (size_t)(wbase + 4*(j) + gr) * 64; \
        X##0 = _p[o];                                                     \
        X##1 = _p[o + 16];                                                \
        X##2 = _p[o + 32];                                                \
        X##3 = _p[o + 48];                                                \
    }

    // compute granule j from X; weights via LDS (lgkmcnt, not vmcnt)
#define COMPG(X, j)                                                       \
    {                                                                     \
        float ap = 0.f, a0 = 0.f, a1 = 0.f, a2 = 0.f, a3 = 0.f;           \
        _Pragma("unroll")                                                 \
        for (int t = 0; t < 4; ++t) {                                     \
            const float4 x = (t == 0) ? X##0 : (t == 1) ? X##1            \
                            : (t == 2) ? X##2 : X##3;                     \
            const int e = o + 16 * t;                                     \
            ap += dot4(x, s_w[e]);                                        \
            a0 += dot4(x, s_w[64 + e]);                                   \
            a1 += dot4(x, s_w[128 + e]);                                  \
            a2 += dot4(x, s_w[192 + e]);                                  \
            a3 += dot4(x, s_w[256 + e]);                                  \
        }                                                                 \
        _Pragma("unroll")                                                 \
        for (int off = 1; off <= 8; off <<= 1) {                          \
            ap += __shfl_xor(ap, off);                                    \
            a0 += __shfl_xor(a0, off);                                    \
            a1 += __shfl_xor(a1, off);                                    \
            a2 += __shfl_xor(a2, off);                                    \
            a3 += __shfl_xor(a3, off);                                    \
        }                                                                 \
        if (o == 0) {                                                     \
            const int r = wbase + 4*(j) + gr;                             \
            const float lg = ap + bp;                                     \
            s_logit[r] = lg;                                              \
            presence_out[tile + r] = lg;                                  \
            const int   ix = r % GG, iy = r / GG;                         \
            const float cx = (ix + 0.5f) / (float)GG;                     \
            const float cy = (iy + 0.5f) / (float)GG;                     \
            s_box[r] = make_float4(a0 + bc0 + cx, a1 + bc1 + cy,          \
                                   a2 + bc2 + cx, a3 + bc3 + cy);         \
        }                                                                 \
    }

    // ---- 2-deep pipelined stream: 12 granules ----
    float4 XA0, XA1, XA2, XA3, XB0, XB1, XB2, XB3;
    LOADG(XA, 0)
    #pragma unroll 1
    for (int j = 0; j < 12; j += 2) {
        LOADG(XB, j + 1)
        COMPG(XA, j)
        if (j + 2 < 12) LOADG(XA, j + 2)
        COMPG(XB, j + 1)
    }

    // ---- tail row wbase+48: lanes 0..15 (gr==0) ----
    if (gr == 0) {
        const int r = wbase + 48;
        const float4* __restrict__ rp = tp + (size_t)r * 64;
        float ap = 0.f, a0 = 0.f, a1 = 0.f, a2 = 0.f, a3 = 0.f;
        #pragma unroll
        for (int t = 0; t < 4; ++t) {
            const float4 x = rp[o + 16 * t];
            const int e = o + 16 * t;
            ap += dot4(x, s_w[e]);
            a0 += dot4(x, s_w[64 + e]);
            a1 += dot4(x, s_w[128 + e]);
            a2 += dot4(x, s_w[192 + e]);
            a3 += dot4(x, s_w[256 + e]);
        }
        #pragma unroll
        for (int off = 1; off <= 8; off <<= 1) {
            ap += __shfl_xor(ap, off);
            a0 += __shfl_xor(a0, off);
            a1 += __shfl_xor(a1, off);
            a2 += __shfl_xor(a2, off);
            a3 += __shfl_xor(a3, off);
        }
        if (o == 0) {
            const float lg = ap + bp;
            s_logit[r] = lg;
            presence_out[tile + r] = lg;
            const int   ix = r % GG, iy = r / GG;
            const float cx = (ix + 0.5f) / (float)GG;
            const float cy = (iy + 0.5f) / (float)GG;
            s_box[r] = make_float4(a0 + bc0 + cx, a1 + bc1 + cy,
                                   a2 + bc2 + cx, a3 + bc3 + cy);
        }
    }

    __syncthreads();
    if (wv != 0) return;

    // ---- Phase 2 (wave 0): top-K argmax over LDS logits ----
    float v[4]; int id[4];
    #pragma unroll
    for (int t = 0; t < 4; ++t) {
        const int r = lane + 64 * t;
        id[t] = r;
        v[t]  = (r < RR) ? s_logit[r] : -1e30f;
    }

    float myv = -1e30f; int myi = 0;
    for (int k = 0; k < KK; ++k) {
        float bv = v[0]; int bi = id[0];
        #pragma unroll
        for (int t = 1; t < 4; ++t)
            if (v[t] > bv || (v[t] == bv && id[t] < bi)) { bv = v[t]; bi = id[t]; }
        #pragma unroll
        for (int off = 32; off; off >>= 1) {
            const float ov = __shfl_xor(bv, off);
            const int   oi = __shfl_xor(bi, off);
            if (ov > bv || (ov == bv && oi < bi)) { bv = ov; bi = oi; }
        }
        #pragma unroll
        for (int t = 0; t < 4; ++t)
            if (id[t] == bi) v[t] = -1e30f;
        if (lane == k) { myv = bv; myi = bi; }
    }

    // ---- box fetch + NMS ----
    float x1 = 0.f, y1 = 0.f, x2 = 0.f, y2 = 0.f, area = 0.f, prob = 0.f;
    int kp = 0;
    if (lane < KK) {
        const float4 b = s_box[myi];
        x1 = b.x; y1 = b.y; x2 = b.z; y2 = b.w;
        area = fmaxf(x2 - x1, 0.f) * fmaxf(y2 - y1, 0.f);
        prob = 1.f / (1.f + expf(-myv));
        kp   = (prob > CONF_) ? 1 : 0;
    }
    for (int i = 0; i < KK; ++i) {
        const int   ki  = __shfl(kp, i);
        const float bx1 = __shfl(x1, i), by1 = __shfl(y1, i);
        const float bx2 = __shfl(x2, i), by2 = __shfl(y2, i);
        const float ai  = __shfl(area, i);
        if (lane > i && lane < KK && ki) {
            const float xx1 = fmaxf(x1, bx1), yy1 = fmaxf(y1, by1);
            const float xx2 = fminf(x2, bx2), yy2 = fminf(y2, by2);
            const float inter = fmaxf(xx2 - xx1, 0.f) * fmaxf(yy2 - yy1, 0.f);
            const float uni   = area + ai - inter;
            const float iou   = inter / fmaxf(uni, 1e-9f);
            if (iou > IOU_THR_) kp = 0;
        }
    }

    // ---- outputs ----
    if (lane < KK) {
        const size_t obase = (size_t)bc * KK + lane;
        const float  kf    = kp ? 1.f : 0.f;
        coords_out[obase * 4 + 0] = x1 * kf;
        coords_out[obase * 4 + 1] = y1 * kf;
        coords_out[obase * 4 + 2] = x2 * kf;
        coords_out[obase * 4 + 3] = y2 * kf;
        probs_out[obase] = prob * kf;
        keep_out[obase]  = kf;
    }
#undef LOADG
#undef COMPG
}

extern "C" void kernel_launch(void* const* d_in, const int* in_sizes, int n_in,
                              void* d_out, int out_size, void* d_ws, size_t ws_size,
                              hipStream_t stream) {
    const float* lf       = (const float*)d_in[0];
    const float* W_coords = (const float*)d_in[1];
    const float* b_coords = (const float*)d_in[2];
    const float* W_pres   = (const float*)d_in[3];
    const float* b_pres   = (const float*)d_in[4];

    float* out          = (float*)d_out;
    float* coords_out   = out + COORDS_OFF;
    float* probs_out    = out + PROBS_OFF;
    float* keep_out     = out + KEEP_OFF;
    float* presence_out = out + PRES_OFF;

    // One block per (b,c); 960 blocks, fully independent (single launch).
    fused_bbox_ldsw<<<BB * CC, 256, 0, stream>>>(
        (const float4*)lf, W_coords, b_coords, W_pres, b_pres,
        coords_out, probs_out, keep_out, presence_out);
}

// Round 10
// 56.856 us; speedup vs baseline: 1.7816x; 1.3306x over previous
//
#include <hip/hip_runtime.h>
#include <hip/hip_bf16.h>
#include <math.h>

// Problem constants (from reference)
#define BB 32
#define CC 30
#define RR 196
#define DD 256
#define KK 20
#define GG 14            // sqrt(RR)
#define CONF_ 0.5f
#define IOU_THR_ 0.3f

constexpr int COORDS_OFF = 0;                // (B,C,K,4)
constexpr int PROBS_OFF  = BB * CC * KK * 4; // 76800
constexpr int KEEP_OFF   = PROBS_OFF + BB * CC * KK;  // 96000
constexpr int PRES_OFF   = KEEP_OFF + BB * CC * KK;   // 115200

typedef float v4f __attribute__((ext_vector_type(4)));

__device__ __forceinline__ float dot4v(v4f a, v4f b) {
    return a[0] * b[0] + a[1] * b[1] + a[2] * b[2] + a[3] * b[3];
}

// Opacity pin: after this, the compiler cannot rematerialize/reload w from
// memory — it must keep the value in VGPRs for its live range.
#define PIN4(w) asm volatile("" : "+v"(w))

// ---------------------------------------------------------------------------
// R9: register-PINNED weights.
// R7/R8 diagnosis: VGPR_Count=64 in both proved the compiler never kept the
// "register" weights resident — it re-loaded all 20 weight float4s from
// global memory EVERY granule. L1-return cost: 20 KB of weight bytes per
// 4 KB of data -> ~10 B/cy/CU -> the invariant ~4 TB/s wall of R1-R7.
// (R8 moved weights to LDS: fixed vmcnt pollution but added 20 KB LDS
// traffic + lgkm stalls -> worse.)
// Fix: 32 lanes/row, 2 taps/lane -> only 10 weight v4f (40 VGPR), loaded
// once and made OPAQUE via empty inline asm ("+v") so they cannot be
// reloaded. Streaming loop: 2 loads per 2-row granule, zero weight traffic.
// Structure otherwise = R5 (passing): one block per (b,c), 4 waves x 49
// rows, phase-2 epilogue on wave 0 from LDS.
// ---------------------------------------------------------------------------
__global__ __launch_bounds__(256, 4) void fused_bbox_pin(
    const v4f*   __restrict__ lf,         // (B*C*R) x 64 v4f
    const float* __restrict__ W_coords,   // 4 x 256
    const float* __restrict__ b_coords,   // 4
    const float* __restrict__ W_pres,     // 256
    const float* __restrict__ b_pres,     // 1
    float* __restrict__ coords_out,
    float* __restrict__ probs_out,
    float* __restrict__ keep_out,
    float* __restrict__ presence_out)
{
    const int bc   = blockIdx.x;
    const int tid  = threadIdx.x;
    const int wv   = tid >> 6;
    const int lane = tid & 63;
    const int o2   = lane & 31;   // v4f slot within row half
    const int hr   = lane >> 5;   // 0: even row of pair, 1: odd row

    __shared__ float s_logit[RR];
    __shared__ v4f   s_box[RR];

    const v4f* __restrict__ Wp4 = reinterpret_cast<const v4f*>(W_pres);
    const v4f* __restrict__ Wc4 = reinterpret_cast<const v4f*>(W_coords);

    // ---- weights: 10 v4f = 40 VGPR, loaded once, PINNED ----
    v4f wp0 = Wp4[o2],        wp1 = Wp4[o2 + 32];
    v4f wa0 = Wc4[o2],        wa1 = Wc4[o2 + 32];
    v4f wb0 = Wc4[64 + o2],   wb1 = Wc4[96 + o2];
    v4f wc0 = Wc4[128 + o2],  wc1 = Wc4[160 + o2];
    v4f wd0 = Wc4[192 + o2],  wd1 = Wc4[224 + o2];
    PIN4(wp0); PIN4(wp1);
    PIN4(wa0); PIN4(wa1);
    PIN4(wb0); PIN4(wb1);
    PIN4(wc0); PIN4(wc1);
    PIN4(wd0); PIN4(wd1);

    const float bp  = b_pres[0];
    const float bc0 = b_coords[0], bc1 = b_coords[1];
    const float bc2 = b_coords[2], bc3 = b_coords[3];

    const size_t tile = (size_t)bc * RR;
    const v4f* __restrict__ tp = lf + tile * 64;
    const int wbase = wv * 49;            // 4 waves x 49 rows = 196

    // ---- main stream: 24 granules of 2 rows (rows wbase+2j+hr) ----
    #pragma unroll 4
    for (int j = 0; j < 24; ++j) {
        const int r = wbase + 2 * j + hr;
        const v4f* __restrict__ rp = tp + (size_t)r * 64;
        const v4f x0 = rp[o2];
        const v4f x1 = rp[o2 + 32];

        float ap = dot4v(x0, wp0) + dot4v(x1, wp1);
        float a0 = dot4v(x0, wa0) + dot4v(x1, wa1);
        float a1 = dot4v(x0, wb0) + dot4v(x1, wb1);
        float a2 = dot4v(x0, wc0) + dot4v(x1, wc1);
        float a3 = dot4v(x0, wd0) + dot4v(x1, wd1);

        #pragma unroll
        for (int off = 1; off <= 16; off <<= 1) {
            ap += __shfl_xor(ap, off);
            a0 += __shfl_xor(a0, off);
            a1 += __shfl_xor(a1, off);
            a2 += __shfl_xor(a2, off);
            a3 += __shfl_xor(a3, off);
        }
        if (o2 == 0) {
            const float lg = ap + bp;
            s_logit[r] = lg;
            presence_out[tile + r] = lg;
            const int   ix = r % GG, iy = r / GG;
            const float cx = (ix + 0.5f) / (float)GG;
            const float cy = (iy + 0.5f) / (float)GG;
            v4f b; b[0] = a0 + bc0 + cx; b[1] = a1 + bc1 + cy;
                   b[2] = a2 + bc2 + cx; b[3] = a3 + bc3 + cy;
            s_box[r] = b;
        }
    }

    // ---- tail row wbase+48: all 64 lanes (hr selects tap half) ----
    {
        const int r = wbase + 48;
        const v4f* __restrict__ rp = tp + (size_t)r * 64;
        const v4f x = rp[o2 + 32 * hr];
        const v4f vp = hr ? wp1 : wp0;
        const v4f va = hr ? wa1 : wa0;
        const v4f vb = hr ? wb1 : wb0;
        const v4f vc = hr ? wc1 : wc0;
        const v4f vd = hr ? wd1 : wd0;
        float ap = dot4v(x, vp);
        float a0 = dot4v(x, va);
        float a1 = dot4v(x, vb);
        float a2 = dot4v(x, vc);
        float a3 = dot4v(x, vd);
        #pragma unroll
        for (int off = 1; off <= 32; off <<= 1) {
            ap += __shfl_xor(ap, off);
            a0 += __shfl_xor(a0, off);
            a1 += __shfl_xor(a1, off);
            a2 += __shfl_xor(a2, off);
            a3 += __shfl_xor(a3, off);
        }
        if (lane == 0) {
            const float lg = ap + bp;
            s_logit[r] = lg;
            presence_out[tile + r] = lg;
            const int   ix = r % GG, iy = r / GG;
            const float cx = (ix + 0.5f) / (float)GG;
            const float cy = (iy + 0.5f) / (float)GG;
            v4f b; b[0] = a0 + bc0 + cx; b[1] = a1 + bc1 + cy;
                   b[2] = a2 + bc2 + cx; b[3] = a3 + bc3 + cy;
            s_box[r] = b;
        }
    }

    __syncthreads();
    if (wv != 0) return;

    // ---- Phase 2 (wave 0): top-K argmax over LDS logits ----
    float v[4]; int id[4];
    #pragma unroll
    for (int t = 0; t < 4; ++t) {
        const int r = lane + 64 * t;
        id[t] = r;
        v[t]  = (r < RR) ? s_logit[r] : -1e30f;
    }

    float myv = -1e30f; int myi = 0;
    for (int k = 0; k < KK; ++k) {
        float bv = v[0]; int bi = id[0];
        #pragma unroll
        for (int t = 1; t < 4; ++t)
            if (v[t] > bv || (v[t] == bv && id[t] < bi)) { bv = v[t]; bi = id[t]; }
        #pragma unroll
        for (int off = 32; off; off >>= 1) {
            const float ov = __shfl_xor(bv, off);
            const int   oi = __shfl_xor(bi, off);
            if (ov > bv || (ov == bv && oi < bi)) { bv = ov; bi = oi; }
        }
        #pragma unroll
        for (int t = 0; t < 4; ++t)
            if (id[t] == bi) v[t] = -1e30f;
        if (lane == k) { myv = bv; myi = bi; }
    }

    // ---- box fetch + NMS ----
    float x1 = 0.f, y1 = 0.f, x2 = 0.f, y2 = 0.f, area = 0.f, prob = 0.f;
    int kp = 0;
    if (lane < KK) {
        const v4f b = s_box[myi];
        x1 = b[0]; y1 = b[1]; x2 = b[2]; y2 = b[3];
        area = fmaxf(x2 - x1, 0.f) * fmaxf(y2 - y1, 0.f);
        prob = 1.f / (1.f + expf(-myv));
        kp   = (prob > CONF_) ? 1 : 0;
    }
    for (int i = 0; i < KK; ++i) {
        const int   ki  = __shfl(kp, i);
        const float bx1 = __shfl(x1, i), by1 = __shfl(y1, i);
        const float bx2 = __shfl(x2, i), by2 = __shfl(y2, i);
        const float ai  = __shfl(area, i);
        if (lane > i && lane < KK && ki) {
            const float xx1 = fmaxf(x1, bx1), yy1 = fmaxf(y1, by1);
            const float xx2 = fminf(x2, bx2), yy2 = fminf(y2, by2);
            const float inter = fmaxf(xx2 - xx1, 0.f) * fmaxf(yy2 - yy1, 0.f);
            const float uni   = area + ai - inter;
            const float iou   = inter / fmaxf(uni, 1e-9f);
            if (iou > IOU_THR_) kp = 0;
        }
    }

    // ---- outputs ----
    if (lane < KK) {
        const size_t obase = (size_t)bc * KK + lane;
        const float  kf    = kp ? 1.f : 0.f;
        coords_out[obase * 4 + 0] = x1 * kf;
        coords_out[obase * 4 + 1] = y1 * kf;
        coords_out[obase * 4 + 2] = x2 * kf;
        coords_out[obase * 4 + 3] = y2 * kf;
        probs_out[obase] = prob * kf;
        keep_out[obase]  = kf;
    }
}

extern "C" void kernel_launch(void* const* d_in, const int* in_sizes, int n_in,
                              void* d_out, int out_size, void* d_ws, size_t ws_size,
                              hipStream_t stream) {
    const float* lf       = (const float*)d_in[0];
    const float* W_coords = (const float*)d_in[1];
    const float* b_coords = (const float*)d_in[2];
    const float* W_pres   = (const float*)d_in[3];
    const float* b_pres   = (const float*)d_in[4];

    float* out          = (float*)d_out;
    float* coords_out   = out + COORDS_OFF;
    float* probs_out    = out + PROBS_OFF;
    float* keep_out     = out + KEEP_OFF;
    float* presence_out = out + PRES_OFF;

    // One block per (b,c); 960 blocks, fully independent (single launch).
    fused_bbox_pin<<<BB * CC, 256, 0, stream>>>(
        (const v4f*)lf, W_coords, b_coords, W_pres, b_pres,
        coords_out, probs_out, keep_out, presence_out);
}

// Round 11
// 53.639 us; speedup vs baseline: 1.8885x; 1.0600x over previous
//
#include <hip/hip_runtime.h>
#include <hip/hip_bf16.h>
#include <math.h>

// Problem constants (from reference)
#define BB 32
#define CC 30
#define RR 196
#define DD 256
#define KK 20
#define GG 14            // sqrt(RR)
#define CONF_ 0.5f
#define IOU_THR_ 0.3f

constexpr int COORDS_OFF = 0;                // (B,C,K,4)
constexpr int PROBS_OFF  = BB * CC * KK * 4; // 76800
constexpr int KEEP_OFF   = PROBS_OFF + BB * CC * KK;  // 96000
constexpr int PRES_OFF   = KEEP_OFF + BB * CC * KK;   // 115200

typedef float v4f __attribute__((ext_vector_type(4)));

__device__ __forceinline__ float dot4v(v4f a, v4f b) {
    return a[0] * b[0] + a[1] * b[1] + a[2] * b[2] + a[3] * b[3];
}

// Opacity pin: forbids rematerializing/reloading w from memory.
#define PIN4(w) asm volatile("" : "+v"(w))

// ---------------------------------------------------------------------------
// R10: R5's exact structure (best baseline, 50.5 µs) + the register fix.
// Unified theory of R1-R9's ~4 TB/s wall: under __launch_bounds__(256,4)'s
// 128-VGPR cap, the live set (20 weight float4 = 80 VGPR + in-flight data +
// accs + addressing ~116+) doesn't fit with scheduling slack, so the
// allocator REMATERIALIZES the loop-invariant weight loads every granule
// (R7 proof: VGPR_Count=64). That re-streams 20 KB of weights per 4 KB of
// data through L1 (~64 B/cy) -> ~27 µs/pass, insensitive to HBM vs L3 —
// matching R7's equal-speed passes. Fix:
//   (a) __launch_bounds__(256,3) -> 168-VGPR budget (live set fits w/ slack)
//   (b) PIN4 makes the weight values opaque (remat illegal)
//   (c) unroll 2 -> two granules' loads (8 KB/wave) overlap
// Occupancy 3 blocks/CU (12 waves) is ample for streaming (fill kernel does
// 7 TB/s at ~3 waves/CU).
// ---------------------------------------------------------------------------
__global__ __launch_bounds__(256, 3) void fused_bbox_fit(
    const v4f*   __restrict__ lf,         // (B*C*R) x 64 v4f
    const float* __restrict__ W_coords,   // 4 x 256
    const float* __restrict__ b_coords,   // 4
    const float* __restrict__ W_pres,     // 256
    const float* __restrict__ b_pres,     // 1
    float* __restrict__ coords_out,
    float* __restrict__ probs_out,
    float* __restrict__ keep_out,
    float* __restrict__ presence_out)
{
    const int bc   = blockIdx.x;
    const int tid  = threadIdx.x;
    const int wv   = tid >> 6;
    const int lane = tid & 63;
    const int gr   = lane >> 4;   // row slot within granule (0..3)
    const int o    = lane & 15;   // sub-lane within row

    __shared__ float s_logit[RR];
    __shared__ v4f   s_box[RR];

    const v4f* __restrict__ Wp4 = reinterpret_cast<const v4f*>(W_pres);
    const v4f* __restrict__ Wc4 = reinterpret_cast<const v4f*>(W_coords);

    // ---- weights: 20 v4f = 80 VGPR, loaded once, PINNED ----
    v4f wp0 = Wp4[o],       wp1 = Wp4[o + 16],      wp2 = Wp4[o + 32],      wp3 = Wp4[o + 48];
    v4f wa0 = Wc4[o],       wa1 = Wc4[o + 16],      wa2 = Wc4[o + 32],      wa3 = Wc4[o + 48];
    v4f wb0 = Wc4[64 + o],  wb1 = Wc4[80 + o],      wb2 = Wc4[96 + o],      wb3 = Wc4[112 + o];
    v4f wc0 = Wc4[128 + o], wc1 = Wc4[144 + o],     wc2 = Wc4[160 + o],     wc3 = Wc4[176 + o];
    v4f wd0 = Wc4[192 + o], wd1 = Wc4[208 + o],     wd2 = Wc4[224 + o],     wd3 = Wc4[240 + o];
    PIN4(wp0); PIN4(wp1); PIN4(wp2); PIN4(wp3);
    PIN4(wa0); PIN4(wa1); PIN4(wa2); PIN4(wa3);
    PIN4(wb0); PIN4(wb1); PIN4(wb2); PIN4(wb3);
    PIN4(wc0); PIN4(wc1); PIN4(wc2); PIN4(wc3);
    PIN4(wd0); PIN4(wd1); PIN4(wd2); PIN4(wd3);

    const float bp  = b_pres[0];
    const float bc0 = b_coords[0], bc1 = b_coords[1];
    const float bc2 = b_coords[2], bc3 = b_coords[3];

    const size_t tile  = (size_t)bc * RR;
    const v4f* __restrict__ tp = lf + tile * 64;
    const int    wbase = wv * 49;         // 4 waves x 49 rows = 196

    // ---- Phase 1: 12 granules of 4 rows (16 lanes/row, 4 taps/lane) ----
    #pragma unroll 2
    for (int j = 0; j < 12; ++j) {
        const int r = wbase + 4 * j + gr;
        const v4f* __restrict__ rp = tp + (size_t)r * 64;

        const v4f x0 = rp[o];
        const v4f x1 = rp[o + 16];
        const v4f x2 = rp[o + 32];
        const v4f x3 = rp[o + 48];

        float ap = dot4v(x0, wp0) + dot4v(x1, wp1) + dot4v(x2, wp2) + dot4v(x3, wp3);
        float a0 = dot4v(x0, wa0) + dot4v(x1, wa1) + dot4v(x2, wa2) + dot4v(x3, wa3);
        float a1 = dot4v(x0, wb0) + dot4v(x1, wb1) + dot4v(x2, wb2) + dot4v(x3, wb3);
        float a2 = dot4v(x0, wc0) + dot4v(x1, wc1) + dot4v(x2, wc2) + dot4v(x3, wc3);
        float a3 = dot4v(x0, wd0) + dot4v(x1, wd1) + dot4v(x2, wd2) + dot4v(x3, wd3);

        #pragma unroll
        for (int off = 1; off <= 8; off <<= 1) {
            ap += __shfl_xor(ap, off);
            a0 += __shfl_xor(a0, off);
            a1 += __shfl_xor(a1, off);
            a2 += __shfl_xor(a2, off);
            a3 += __shfl_xor(a3, off);
        }
        if (o == 0) {
            const float lg = ap + bp;
            s_logit[r] = lg;
            presence_out[tile + r] = lg;
            const int   ix = r % GG, iy = r / GG;
            const float cx = (ix + 0.5f) / (float)GG;
            const float cy = (iy + 0.5f) / (float)GG;
            v4f b; b[0] = a0 + bc0 + cx; b[1] = a1 + bc1 + cy;
                   b[2] = a2 + bc2 + cx; b[3] = a3 + bc3 + cy;
            s_box[r] = b;
        }
    }

    // ---- Phase 1 tail: row wbase+48, lanes 0..15 only ----
    if (gr == 0) {
        const int r = wbase + 48;
        const v4f* __restrict__ rp = tp + (size_t)r * 64;
        const v4f x0 = rp[o];
        const v4f x1 = rp[o + 16];
        const v4f x2 = rp[o + 32];
        const v4f x3 = rp[o + 48];

        float ap = dot4v(x0, wp0) + dot4v(x1, wp1) + dot4v(x2, wp2) + dot4v(x3, wp3);
        float a0 = dot4v(x0, wa0) + dot4v(x1, wa1) + dot4v(x2, wa2) + dot4v(x3, wa3);
        float a1 = dot4v(x0, wb0) + dot4v(x1, wb1) + dot4v(x2, wb2) + dot4v(x3, wb3);
        float a2 = dot4v(x0, wc0) + dot4v(x1, wc1) + dot4v(x2, wc2) + dot4v(x3, wc3);
        float a3 = dot4v(x0, wd0) + dot4v(x1, wd1) + dot4v(x2, wd2) + dot4v(x3, wd3);

        #pragma unroll
        for (int off = 1; off <= 8; off <<= 1) {
            ap += __shfl_xor(ap, off);
            a0 += __shfl_xor(a0, off);
            a1 += __shfl_xor(a1, off);
            a2 += __shfl_xor(a2, off);
            a3 += __shfl_xor(a3, off);
        }
        if (o == 0) {
            const float lg = ap + bp;
            s_logit[r] = lg;
            presence_out[tile + r] = lg;
            const int   ix = r % GG, iy = r / GG;
            const float cx = (ix + 0.5f) / (float)GG;
            const float cy = (iy + 0.5f) / (float)GG;
            v4f b; b[0] = a0 + bc0 + cx; b[1] = a1 + bc1 + cy;
                   b[2] = a2 + bc2 + cx; b[3] = a3 + bc3 + cy;
            s_box[r] = b;
        }
    }

    __syncthreads();
    if (wv != 0) return;

    // ---- Phase 2 (wave 0): top-K argmax over LDS logits ----
    float v[4]; int id[4];
    #pragma unroll
    for (int t = 0; t < 4; ++t) {
        const int r = lane + 64 * t;
        id[t] = r;
        v[t]  = (r < RR) ? s_logit[r] : -1e30f;
    }

    float myv = -1e30f; int myi = 0;
    for (int k = 0; k < KK; ++k) {
        float bv = v[0]; int bi = id[0];
        #pragma unroll
        for (int t = 1; t < 4; ++t)
            if (v[t] > bv || (v[t] == bv && id[t] < bi)) { bv = v[t]; bi = id[t]; }
        #pragma unroll
        for (int off = 32; off; off >>= 1) {
            const float ov = __shfl_xor(bv, off);
            const int   oi = __shfl_xor(bi, off);
            if (ov > bv || (ov == bv && oi < bi)) { bv = ov; bi = oi; }
        }
        #pragma unroll
        for (int t = 0; t < 4; ++t)
            if (id[t] == bi) v[t] = -1e30f;
        if (lane == k) { myv = bv; myi = bi; }
    }

    // ---- box fetch + NMS ----
    float x1 = 0.f, y1 = 0.f, x2 = 0.f, y2 = 0.f, area = 0.f, prob = 0.f;
    int kp = 0;
    if (lane < KK) {
        const v4f b = s_box[myi];
        x1 = b[0]; y1 = b[1]; x2 = b[2]; y2 = b[3];
        area = fmaxf(x2 - x1, 0.f) * fmaxf(y2 - y1, 0.f);
        prob = 1.f / (1.f + expf(-myv));
        kp   = (prob > CONF_) ? 1 : 0;
    }
    for (int i = 0; i < KK; ++i) {
        const int   ki  = __shfl(kp, i);
        const float bx1 = __shfl(x1, i), by1 = __shfl(y1, i);
        const float bx2 = __shfl(x2, i), by2 = __shfl(y2, i);
        const float ai  = __shfl(area, i);
        if (lane > i && lane < KK && ki) {
            const float xx1 = fmaxf(x1, bx1), yy1 = fmaxf(y1, by1);
            const float xx2 = fminf(x2, bx2), yy2 = fminf(y2, by2);
            const float inter = fmaxf(xx2 - xx1, 0.f) * fmaxf(yy2 - yy1, 0.f);
            const float uni   = area + ai - inter;
            const float iou   = inter / fmaxf(uni, 1e-9f);
            if (iou > IOU_THR_) kp = 0;
        }
    }

    // ---- outputs ----
    if (lane < KK) {
        const size_t obase = (size_t)bc * KK + lane;
        const float  kf    = kp ? 1.f : 0.f;
        coords_out[obase * 4 + 0] = x1 * kf;
        coords_out[obase * 4 + 1] = y1 * kf;
        coords_out[obase * 4 + 2] = x2 * kf;
        coords_out[obase * 4 + 3] = y2 * kf;
        probs_out[obase] = prob * kf;
        keep_out[obase]  = kf;
    }
}

extern "C" void kernel_launch(void* const* d_in, const int* in_sizes, int n_in,
                              void* d_out, int out_size, void* d_ws, size_t ws_size,
                              hipStream_t stream) {
    const float* lf       = (const float*)d_in[0];
    const float* W_coords = (const float*)d_in[1];
    const float* b_coords = (const float*)d_in[2];
    const float* W_pres   = (const float*)d_in[3];
    const float* b_pres   = (const float*)d_in[4];

    float* out          = (float*)d_out;
    float* coords_out   = out + COORDS_OFF;
    float* probs_out    = out + PROBS_OFF;
    float* keep_out     = out + KEEP_OFF;
    float* presence_out = out + PRES_OFF;

    // One block per (b,c); 960 blocks, fully independent (single launch).
    fused_bbox_fit<<<BB * CC, 256, 0, stream>>>(
        (const v4f*)lf, W_coords, b_coords, W_pres, b_pres,
        coords_out, probs_out, keep_out, presence_out);
}

// Round 12
// 53.117 us; speedup vs baseline: 1.9070x; 1.0098x over previous
//
#include <hip/hip_runtime.h>
#include <hip/hip_bf16.h>
#include <math.h>

// Problem constants (from reference)
#define BB 32
#define CC 30
#define RR 196
#define DD 256
#define KK 20
#define GG 14            // sqrt(RR)
#define CONF_ 0.5f
#define IOU_THR_ 0.3f

constexpr int COORDS_OFF = 0;                // (B,C,K,4)
constexpr int PROBS_OFF  = BB * CC * KK * 4; // 76800
constexpr int KEEP_OFF   = PROBS_OFF + BB * CC * KK;  // 96000
constexpr int PRES_OFF   = KEEP_OFF + BB * CC * KK;   // 115200

typedef float v4f __attribute__((ext_vector_type(4)));

__device__ __forceinline__ float dot4v(v4f a, v4f b) {
    return a[0] * b[0] + a[1] * b[1] + a[2] * b[2] + a[3] * b[3];
}

// Opacity pin: forbids rematerializing/reloading w from memory.
#define PIN4(w) asm volatile("" : "+v"(w))

// ---------------------------------------------------------------------------
// R11: global_load_lds streaming — data NEVER enters VGPRs.
// Synthesis of R1-R10: every variant kept in-flight data in VGPRs alongside
// the 80-VGPR weight set; under every budget the allocator either
// rematerialized weight loads (R7: VGPR=64, vmcnt pollution + L1 weight
// traffic) or serialized the stream -> invariant ~4 TB/s. Here the data path
// is DMA: 13 chunks x 16 rows, double-buffered in LDS (32 KB), staged with
// __builtin_amdgcn_global_load_lds width=16 (1 KB/instr, linear LDS dest =
// row-major). Compute reads x from LDS (lgkmcnt — independent of the DMA
// vmcnt queue); weights stay PINned in regs with slack (no data regs live).
// 4 blocks/CU (LDS-limited) -> up to 64 KB DMA in flight per CU, >> the
// ~22 KB Little's-law need for 6 TB/s; __syncthreads' vmcnt(0) drain is
// per-block and overlapped across the 4 resident blocks.
// Epilogue (phase 2) identical to the passing R5/R10 kernel.
// ---------------------------------------------------------------------------
__global__ __launch_bounds__(256, 3) void fused_bbox_dma(
    const float* __restrict__ lf,         // (B*C*R) x 256 floats
    const float* __restrict__ W_coords,   // 4 x 256
    const float* __restrict__ b_coords,   // 4
    const float* __restrict__ W_pres,     // 256
    const float* __restrict__ b_pres,     // 1
    float* __restrict__ coords_out,
    float* __restrict__ probs_out,
    float* __restrict__ keep_out,
    float* __restrict__ presence_out)
{
    const int bc   = blockIdx.x;
    const int tid  = threadIdx.x;
    const int wv   = tid >> 6;
    const int lane = tid & 63;
    const int gr   = lane >> 4;   // row slot within granule (0..3)
    const int o    = lane & 15;   // sub-lane within row

    __shared__ v4f   Xb[2][16][64];   // 32 KB double-buffered data chunks
    __shared__ float s_logit[RR];
    __shared__ v4f   s_box[RR];

    const v4f* __restrict__ Wp4 = reinterpret_cast<const v4f*>(W_pres);
    const v4f* __restrict__ Wc4 = reinterpret_cast<const v4f*>(W_coords);

    // ---- weights: 20 v4f = 80 VGPR, loaded once, PINNED (fits: no data
    //      registers are live in the stream loop) ----
    v4f wp0 = Wp4[o],       wp1 = Wp4[o + 16],  wp2 = Wp4[o + 32],  wp3 = Wp4[o + 48];
    v4f wa0 = Wc4[o],       wa1 = Wc4[o + 16],  wa2 = Wc4[o + 32],  wa3 = Wc4[o + 48];
    v4f wb0 = Wc4[64 + o],  wb1 = Wc4[80 + o],  wb2 = Wc4[96 + o],  wb3 = Wc4[112 + o];
    v4f wc0 = Wc4[128 + o], wc1 = Wc4[144 + o], wc2 = Wc4[160 + o], wc3 = Wc4[176 + o];
    v4f wd0 = Wc4[192 + o], wd1 = Wc4[208 + o], wd2 = Wc4[224 + o], wd3 = Wc4[240 + o];
    PIN4(wp0); PIN4(wp1); PIN4(wp2); PIN4(wp3);
    PIN4(wa0); PIN4(wa1); PIN4(wa2); PIN4(wa3);
    PIN4(wb0); PIN4(wb1); PIN4(wb2); PIN4(wb3);
    PIN4(wc0); PIN4(wc1); PIN4(wc2); PIN4(wc3);
    PIN4(wd0); PIN4(wd1); PIN4(wd2); PIN4(wd3);

    const float bp  = b_pres[0];
    const float bc0 = b_coords[0], bc1 = b_coords[1];
    const float bc2 = b_coords[2], bc3 = b_coords[3];

    const size_t tile = (size_t)bc * RR;
    const char* __restrict__ tbase =
        reinterpret_cast<const char*>(lf) + tile * (DD * 4);

    // stage chunk c (tile rows 16c..16c+15, clamped in-tile) into buffer b.
    // One instruction = one row: 64 lanes x 16 B -> 1 KB linear LDS row.
#define STAGE(c_, b_)                                                        \
    {                                                                        \
        _Pragma("unroll")                                                    \
        for (int i_ = 0; i_ < 4; ++i_) {                                     \
            int trow_ = 16 * (c_) + 4 * wv + i_;                             \
            if (trow_ > RR - 1) trow_ = RR - 1;                              \
            const char* src_ = tbase + (size_t)trow_ * 1024 + (size_t)lane * 16; \
            __builtin_amdgcn_global_load_lds(                                \
                (const __attribute__((address_space(1))) void*)src_,         \
                (__attribute__((address_space(3))) void*)&Xb[b_][4 * wv + i_][0], \
                16, 0, 0);                                                   \
        }                                                                    \
    }

    // compute chunk c from buffer b: wave wv owns LDS rows 4wv..4wv+3.
#define COMPUTE(c_, b_)                                                      \
    {                                                                        \
        const int jj_ = 4 * wv + gr;                                         \
        const int r_  = 16 * (c_) + jj_;                                     \
        if (r_ < RR) {                                                       \
            const v4f x0 = Xb[b_][jj_][o];                                   \
            const v4f x1 = Xb[b_][jj_][o + 16];                              \
            const v4f x2 = Xb[b_][jj_][o + 32];                              \
            const v4f x3 = Xb[b_][jj_][o + 48];                              \
            float ap = dot4v(x0, wp0) + dot4v(x1, wp1) + dot4v(x2, wp2) + dot4v(x3, wp3); \
            float a0 = dot4v(x0, wa0) + dot4v(x1, wa1) + dot4v(x2, wa2) + dot4v(x3, wa3); \
            float a1 = dot4v(x0, wb0) + dot4v(x1, wb1) + dot4v(x2, wb2) + dot4v(x3, wb3); \
            float a2 = dot4v(x0, wc0) + dot4v(x1, wc1) + dot4v(x2, wc2) + dot4v(x3, wc3); \
            float a3 = dot4v(x0, wd0) + dot4v(x1, wd1) + dot4v(x2, wd2) + dot4v(x3, wd3); \
            _Pragma("unroll")                                                \
            for (int off_ = 1; off_ <= 8; off_ <<= 1) {                      \
                ap += __shfl_xor(ap, off_);                                  \
                a0 += __shfl_xor(a0, off_);                                  \
                a1 += __shfl_xor(a1, off_);                                  \
                a2 += __shfl_xor(a2, off_);                                  \
                a3 += __shfl_xor(a3, off_);                                  \
            }                                                                \
            if (o == 0) {                                                    \
                const float lg_ = ap + bp;                                   \
                s_logit[r_] = lg_;                                           \
                presence_out[tile + r_] = lg_;                               \
                const int   ix_ = r_ % GG, iy_ = r_ / GG;                    \
                const float cx_ = (ix_ + 0.5f) / (float)GG;                  \
                const float cy_ = (iy_ + 0.5f) / (float)GG;                  \
                v4f b__; b__[0] = a0 + bc0 + cx_; b__[1] = a1 + bc1 + cy_;   \
                         b__[2] = a2 + bc2 + cx_; b__[3] = a3 + bc3 + cy_;   \
                s_box[r_] = b__;                                             \
            }                                                                \
        }                                                                    \
    }

    // ---- Phase 1: 13 chunks, double-buffered DMA pipeline ----
    STAGE(0, 0);
    __syncthreads();                       // chunk 0 landed
    #pragma unroll 1
    for (int c = 0; c < 13; ++c) {
        if (c + 1 < 13) STAGE(c + 1, (c + 1) & 1);  // DMA next chunk (other buffer)
        COMPUTE(c, c & 1);                           // compute current from LDS
        __syncthreads();                             // next chunk landed; buffer reusable
    }

    if (wv != 0) return;

    // ---- Phase 2 (wave 0): top-K argmax over LDS logits ----
    float v[4]; int id[4];
    #pragma unroll
    for (int t = 0; t < 4; ++t) {
        const int r = lane + 64 * t;
        id[t] = r;
        v[t]  = (r < RR) ? s_logit[r] : -1e30f;
    }

    float myv = -1e30f; int myi = 0;
    for (int k = 0; k < KK; ++k) {
        float bv = v[0]; int bi = id[0];
        #pragma unroll
        for (int t = 1; t < 4; ++t)
            if (v[t] > bv || (v[t] == bv && id[t] < bi)) { bv = v[t]; bi = id[t]; }
        #pragma unroll
        for (int off = 32; off; off >>= 1) {
            const float ov = __shfl_xor(bv, off);
            const int   oi = __shfl_xor(bi, off);
            if (ov > bv || (ov == bv && oi < bi)) { bv = ov; bi = oi; }
        }
        #pragma unroll
        for (int t = 0; t < 4; ++t)
            if (id[t] == bi) v[t] = -1e30f;
        if (lane == k) { myv = bv; myi = bi; }
    }

    // ---- box fetch + NMS ----
    float x1 = 0.f, y1 = 0.f, x2 = 0.f, y2 = 0.f, area = 0.f, prob = 0.f;
    int kp = 0;
    if (lane < KK) {
        const v4f b = s_box[myi];
        x1 = b[0]; y1 = b[1]; x2 = b[2]; y2 = b[3];
        area = fmaxf(x2 - x1, 0.f) * fmaxf(y2 - y1, 0.f);
        prob = 1.f / (1.f + expf(-myv));
        kp   = (prob > CONF_) ? 1 : 0;
    }
    for (int i = 0; i < KK; ++i) {
        const int   ki  = __shfl(kp, i);
        const float bx1 = __shfl(x1, i), by1 = __shfl(y1, i);
        const float bx2 = __shfl(x2, i), by2 = __shfl(y2, i);
        const float ai  = __shfl(area, i);
        if (lane > i && lane < KK && ki) {
            const float xx1 = fmaxf(x1, bx1), yy1 = fmaxf(y1, by1);
            const float xx2 = fminf(x2, bx2), yy2 = fminf(y2, by2);
            const float inter = fmaxf(xx2 - xx1, 0.f) * fmaxf(yy2 - yy1, 0.f);
            const float uni   = area + ai - inter;
            const float iou   = inter / fmaxf(uni, 1e-9f);
            if (iou > IOU_THR_) kp = 0;
        }
    }

    // ---- outputs ----
    if (lane < KK) {
        const size_t obase = (size_t)bc * KK + lane;
        const float  kf    = kp ? 1.f : 0.f;
        coords_out[obase * 4 + 0] = x1 * kf;
        coords_out[obase * 4 + 1] = y1 * kf;
        coords_out[obase * 4 + 2] = x2 * kf;
        coords_out[obase * 4 + 3] = y2 * kf;
        probs_out[obase] = prob * kf;
        keep_out[obase]  = kf;
    }
#undef STAGE
#undef COMPUTE
}

extern "C" void kernel_launch(void* const* d_in, const int* in_sizes, int n_in,
                              void* d_out, int out_size, void* d_ws, size_t ws_size,
                              hipStream_t stream) {
    const float* lf       = (const float*)d_in[0];
    const float* W_coords = (const float*)d_in[1];
    const float* b_coords = (const float*)d_in[2];
    const float* W_pres   = (const float*)d_in[3];
    const float* b_pres   = (const float*)d_in[4];

    float* out          = (float*)d_out;
    float* coords_out   = out + COORDS_OFF;
    float* probs_out    = out + PROBS_OFF;
    float* keep_out     = out + KEEP_OFF;
    float* presence_out = out + PRES_OFF;

    // One block per (b,c); 960 blocks, fully independent (single launch).
    fused_bbox_dma<<<BB * CC, 256, 0, stream>>>(
        lf, W_coords, b_coords, W_pres, b_pres,
        coords_out, probs_out, keep_out, presence_out);
}

// Round 13
// 52.456 us; speedup vs baseline: 1.9310x; 1.0126x over previous
//
#include <hip/hip_runtime.h>
#include <hip/hip_bf16.h>
#include <math.h>

// Problem constants (from reference)
#define BB 32
#define CC 30
#define RR 196
#define DD 256
#define KK 20
#define GG 14            // sqrt(RR)
#define CONF_ 0.5f
#define IOU_THR_ 0.3f

constexpr int COORDS_OFF = 0;                // (B,C,K,4)
constexpr int PROBS_OFF  = BB * CC * KK * 4; // 76800
constexpr int KEEP_OFF   = PROBS_OFF + BB * CC * KK;  // 96000
constexpr int PRES_OFF   = KEEP_OFF + BB * CC * KK;   // 115200

typedef float v4f __attribute__((ext_vector_type(4)));

__device__ __forceinline__ float dot4v(v4f a, v4f b) {
    return a[0] * b[0] + a[1] * b[1] + a[2] * b[2] + a[3] * b[3];
}

// Non-temporal data load: sets the nt cache bits -> the read-once lf stream
// does not allocate L2/L3 lines. R1-R11 synthesis: consume side proven good
// for 7.7 TB/s (R7's L3-served passes), but every HBM-read variant caps at
// ~3.9 TB/s ~= half the fill kernel's 7 TB/s write rate. The one asymmetry
// never tested: reads ALLOCATE cache lines on fill, writes stream through.
#define NTLOAD(p) __builtin_nontemporal_load(p)

// ---------------------------------------------------------------------------
// R12 = R5 exactly (best passing baseline, 50.46 µs) + non-temporal lf loads.
// One kernel, one block per (b,c) tile, 960 blocks x 256 threads.
//   Phase 1: 16 lanes/row, 4 rows/granule, 12 granules + tail per wave.
//   Phase 2: wave-0 epilogue (top-K argmax, NMS) from LDS.
// ---------------------------------------------------------------------------
__global__ __launch_bounds__(256, 4) void fused_bbox_nt(
    const v4f*   __restrict__ lf,         // (B*C*R) x 64 v4f
    const float* __restrict__ W_coords,   // 4 x 256
    const float* __restrict__ b_coords,   // 4
    const float* __restrict__ W_pres,     // 256
    const float* __restrict__ b_pres,     // 1
    float* __restrict__ coords_out,
    float* __restrict__ probs_out,
    float* __restrict__ keep_out,
    float* __restrict__ presence_out)
{
    const int bc   = blockIdx.x;
    const int tid  = threadIdx.x;
    const int wv   = tid >> 6;
    const int lane = tid & 63;
    const int gr   = lane >> 4;   // row slot within granule (0..3)
    const int o    = lane & 15;   // sub-lane within row

    __shared__ float s_logit[RR];
    __shared__ v4f   s_box[RR];

    const v4f* __restrict__ Wp4 = reinterpret_cast<const v4f*>(W_pres);
    const v4f* __restrict__ Wc4 = reinterpret_cast<const v4f*>(W_coords);

    // Weights: loaded once per iteration scope by the compiler's choosing
    // (R5 config — do NOT perturb; R5 is the best measured baseline).
    v4f wp[4], w0[4], w1[4], w2[4], w3[4];
    #pragma unroll
    for (int t = 0; t < 4; ++t) {
        wp[t] = Wp4[o + 16 * t];
        w0[t] = Wc4[      o + 16 * t];
        w1[t] = Wc4[ 64 + o + 16 * t];
        w2[t] = Wc4[128 + o + 16 * t];
        w3[t] = Wc4[192 + o + 16 * t];
    }
    const float bp  = b_pres[0];
    const float bc0 = b_coords[0], bc1 = b_coords[1];
    const float bc2 = b_coords[2], bc3 = b_coords[3];

    const size_t tile  = (size_t)bc * RR;
    const v4f* __restrict__ tp = lf + tile * 64;
    const int    wbase = wv * 49;         // 4 waves x 49 rows = 196

    // ---- Phase 1: 12 granules of 4 rows ----
    #pragma unroll 1
    for (int j = 0; j < 12; ++j) {
        const int r = wbase + 4 * j + gr;
        const v4f* __restrict__ rp = tp + (size_t)r * 64;

        float ap = 0.f, a0 = 0.f, a1 = 0.f, a2 = 0.f, a3 = 0.f;
        #pragma unroll
        for (int t = 0; t < 4; ++t) {
            const v4f x = NTLOAD(rp + o + 16 * t);
            ap += dot4v(x, wp[t]);
            a0 += dot4v(x, w0[t]);
            a1 += dot4v(x, w1[t]);
            a2 += dot4v(x, w2[t]);
            a3 += dot4v(x, w3[t]);
        }
        #pragma unroll
        for (int off = 1; off <= 8; off <<= 1) {
            ap += __shfl_xor(ap, off);
            a0 += __shfl_xor(a0, off);
            a1 += __shfl_xor(a1, off);
            a2 += __shfl_xor(a2, off);
            a3 += __shfl_xor(a3, off);
        }
        if (o == 0) {
            const float lg = ap + bp;
            s_logit[r] = lg;
            presence_out[tile + r] = lg;
            const int   ix = r % GG, iy = r / GG;
            const float cx = (ix + 0.5f) / (float)GG;
            const float cy = (iy + 0.5f) / (float)GG;
            v4f b; b[0] = a0 + bc0 + cx; b[1] = a1 + bc1 + cy;
                   b[2] = a2 + bc2 + cx; b[3] = a3 + bc3 + cy;
            s_box[r] = b;
        }
    }

    // ---- Phase 1 tail: row wbase+48, lanes 0..15 only ----
    if (gr == 0) {
        const int r = wbase + 48;
        const v4f* __restrict__ rp = tp + (size_t)r * 64;
        float ap = 0.f, a0 = 0.f, a1 = 0.f, a2 = 0.f, a3 = 0.f;
        #pragma unroll
        for (int t = 0; t < 4; ++t) {
            const v4f x = NTLOAD(rp + o + 16 * t);
            ap += dot4v(x, wp[t]);
            a0 += dot4v(x, w0[t]);
            a1 += dot4v(x, w1[t]);
            a2 += dot4v(x, w2[t]);
            a3 += dot4v(x, w3[t]);
        }
        #pragma unroll
        for (int off = 1; off <= 8; off <<= 1) {
            ap += __shfl_xor(ap, off);
            a0 += __shfl_xor(a0, off);
            a1 += __shfl_xor(a1, off);
            a2 += __shfl_xor(a2, off);
            a3 += __shfl_xor(a3, off);
        }
        if (o == 0) {
            const float lg = ap + bp;
            s_logit[r] = lg;
            presence_out[tile + r] = lg;
            const int   ix = r % GG, iy = r / GG;
            const float cx = (ix + 0.5f) / (float)GG;
            const float cy = (iy + 0.5f) / (float)GG;
            v4f b; b[0] = a0 + bc0 + cx; b[1] = a1 + bc1 + cy;
                   b[2] = a2 + bc2 + cx; b[3] = a3 + bc3 + cy;
            s_box[r] = b;
        }
    }

    __syncthreads();
    if (wv != 0) return;

    // ---- Phase 2 (wave 0): top-K argmax over LDS logits ----
    float v[4]; int id[4];
    #pragma unroll
    for (int t = 0; t < 4; ++t) {
        const int r = lane + 64 * t;
        id[t] = r;
        v[t]  = (r < RR) ? s_logit[r] : -1e30f;
    }

    float myv = -1e30f; int myi = 0;
    for (int k = 0; k < KK; ++k) {
        float bv = v[0]; int bi = id[0];
        #pragma unroll
        for (int t = 1; t < 4; ++t)
            if (v[t] > bv || (v[t] == bv && id[t] < bi)) { bv = v[t]; bi = id[t]; }
        #pragma unroll
        for (int off = 32; off; off >>= 1) {
            const float ov = __shfl_xor(bv, off);
            const int   oi = __shfl_xor(bi, off);
            if (ov > bv || (ov == bv && oi < bi)) { bv = ov; bi = oi; }
        }
        #pragma unroll
        for (int t = 0; t < 4; ++t)
            if (id[t] == bi) v[t] = -1e30f;
        if (lane == k) { myv = bv; myi = bi; }
    }

    // ---- box fetch + NMS ----
    float x1 = 0.f, y1 = 0.f, x2 = 0.f, y2 = 0.f, area = 0.f, prob = 0.f;
    int kp = 0;
    if (lane < KK) {
        const v4f b = s_box[myi];
        x1 = b[0]; y1 = b[1]; x2 = b[2]; y2 = b[3];
        area = fmaxf(x2 - x1, 0.f) * fmaxf(y2 - y1, 0.f);
        prob = 1.f / (1.f + expf(-myv));
        kp   = (prob > CONF_) ? 1 : 0;
    }
    for (int i = 0; i < KK; ++i) {
        const int   ki  = __shfl(kp, i);
        const float bx1 = __shfl(x1, i), by1 = __shfl(y1, i);
        const float bx2 = __shfl(x2, i), by2 = __shfl(y2, i);
        const float ai  = __shfl(area, i);
        if (lane > i && lane < KK && ki) {
            const float xx1 = fmaxf(x1, bx1), yy1 = fmaxf(y1, by1);
            const float xx2 = fminf(x2, bx2), yy2 = fminf(y2, by2);
            const float inter = fmaxf(xx2 - xx1, 0.f) * fmaxf(yy2 - yy1, 0.f);
            const float uni   = area + ai - inter;
            const float iou   = inter / fmaxf(uni, 1e-9f);
            if (iou > IOU_THR_) kp = 0;
        }
    }

    // ---- outputs ----
    if (lane < KK) {
        const size_t obase = (size_t)bc * KK + lane;
        const float  kf    = kp ? 1.f : 0.f;
        coords_out[obase * 4 + 0] = x1 * kf;
        coords_out[obase * 4 + 1] = y1 * kf;
        coords_out[obase * 4 + 2] = x2 * kf;
        coords_out[obase * 4 + 3] = y2 * kf;
        probs_out[obase] = prob * kf;
        keep_out[obase]  = kf;
    }
}

extern "C" void kernel_launch(void* const* d_in, const int* in_sizes, int n_in,
                              void* d_out, int out_size, void* d_ws, size_t ws_size,
                              hipStream_t stream) {
    const float* lf       = (const float*)d_in[0];
    const float* W_coords = (const float*)d_in[1];
    const float* b_coords = (const float*)d_in[2];
    const float* W_pres   = (const float*)d_in[3];
    const float* b_pres   = (const float*)d_in[4];

    float* out          = (float*)d_out;
    float* coords_out   = out + COORDS_OFF;
    float* probs_out    = out + PROBS_OFF;
    float* keep_out     = out + KEEP_OFF;
    float* presence_out = out + PRES_OFF;

    // One block per (b,c); 960 blocks, fully independent (single launch).
    fused_bbox_nt<<<BB * CC, 256, 0, stream>>>(
        (const v4f*)lf, W_coords, b_coords, W_pres, b_pres,
        coords_out, probs_out, keep_out, presence_out);
}

// Round 14
// 50.091 us; speedup vs baseline: 2.0222x; 1.0472x over previous
//
#include <hip/hip_runtime.h>
#include <hip/hip_bf16.h>
#include <math.h>

// Problem constants (from reference)
#define BB 32
#define CC 30
#define RR 196
#define DD 256
#define KK 20
#define GG 14            // sqrt(RR)
#define CONF_ 0.5f
#define IOU_THR_ 0.3f

constexpr int COORDS_OFF = 0;                // (B,C,K,4)
constexpr int PROBS_OFF  = BB * CC * KK * 4; // 76800
constexpr int KEEP_OFF   = PROBS_OFF + BB * CC * KK;  // 96000
constexpr int PRES_OFF   = KEEP_OFF + BB * CC * KK;   // 115200

__device__ __forceinline__ float dot4(float4 a, float4 b) {
    return a.x * b.x + a.y * b.y + a.z * b.z + a.w * b.w;
}

// ---------------------------------------------------------------------------
// FINAL (= R5, best measured: 50.46 µs). One kernel, one block per (b,c)
// tile, 960 blocks x 256 threads.
//   Phase 1 (all 4 waves): stream the tile's 196 rows once; per row compute
//     presence logit + all 4 coord dots (pure VALU, zero extra HBM).
//     16 lanes/row, 4 rows/granule, 12 granules + tail per wave.
//   Phase 2 (wave 0): top-K argmax over the 196 LDS logits (sigmoid is
//     monotone), box assembly from LDS, lockstep NMS via shuffles, outputs.
//
// Roofline evidence (R0-R12): 13 structural variants (reg/LDS/DMA/NT loads,
// 1-2 kernels, occupancy 8-16 waves/CU, pipeline depth 1-4) all cap at
// 3.8-4.3 TB/s streaming read. Consume side proven non-binding (VALUBusy
// ~18%; L3-resident re-reads no faster -> cap is the L2->CU return path).
// 192.7 MB / 4.2 TB/s + ~4 µs epilogue = ~50 µs = this kernel.
// ---------------------------------------------------------------------------
__global__ __launch_bounds__(256, 4) void fused_bbox_final(
    const float4* __restrict__ lf,        // (B*C*R) x 64 float4
    const float*  __restrict__ W_coords,  // 4 x 256
    const float*  __restrict__ b_coords,  // 4
    const float*  __restrict__ W_pres,    // 256
    const float*  __restrict__ b_pres,    // 1
    float* __restrict__ coords_out,
    float* __restrict__ probs_out,
    float* __restrict__ keep_out,
    float* __restrict__ presence_out)
{
    const int bc   = blockIdx.x;
    const int tid  = threadIdx.x;
    const int wv   = tid >> 6;
    const int lane = tid & 63;
    const int gr   = lane >> 4;   // row slot within granule (0..3)
    const int o    = lane & 15;   // sub-lane within row

    __shared__ float  s_logit[RR];
    __shared__ float4 s_box[RR];

    const float4* __restrict__ Wp4 = reinterpret_cast<const float4*>(W_pres);
    const float4* __restrict__ Wc4 = reinterpret_cast<const float4*>(W_coords);

    float4 wp[4], w0[4], w1[4], w2[4], w3[4];
    #pragma unroll
    for (int t = 0; t < 4; ++t) {
        wp[t] = Wp4[o + 16 * t];
        w0[t] = Wc4[      o + 16 * t];
        w1[t] = Wc4[ 64 + o + 16 * t];
        w2[t] = Wc4[128 + o + 16 * t];
        w3[t] = Wc4[192 + o + 16 * t];
    }
    const float bp  = b_pres[0];
    const float bc0 = b_coords[0], bc1 = b_coords[1];
    const float bc2 = b_coords[2], bc3 = b_coords[3];

    const size_t tile  = (size_t)bc * RR;
    const int    wbase = wv * 49;         // 4 waves x 49 rows = 196

    // ---- Phase 1: 12 granules of 4 rows ----
    #pragma unroll 1
    for (int j = 0; j < 12; ++j) {
        const int r = wbase + 4 * j + gr;
        const float4* __restrict__ rp = lf + (tile + r) * 64;

        float ap = 0.f, a0 = 0.f, a1 = 0.f, a2 = 0.f, a3 = 0.f;
        #pragma unroll
        for (int t = 0; t < 4; ++t) {
            const float4 x = rp[o + 16 * t];
            ap += dot4(x, wp[t]);
            a0 += dot4(x, w0[t]);
            a1 += dot4(x, w1[t]);
            a2 += dot4(x, w2[t]);
            a3 += dot4(x, w3[t]);
        }
        #pragma unroll
        for (int off = 1; off <= 8; off <<= 1) {
            ap += __shfl_xor(ap, off);
            a0 += __shfl_xor(a0, off);
            a1 += __shfl_xor(a1, off);
            a2 += __shfl_xor(a2, off);
            a3 += __shfl_xor(a3, off);
        }
        if (o == 0) {
            const float lg = ap + bp;
            s_logit[r] = lg;
            presence_out[tile + r] = lg;
            const int   ix = r % GG, iy = r / GG;
            const float cx = (ix + 0.5f) / (float)GG;
            const float cy = (iy + 0.5f) / (float)GG;
            s_box[r] = make_float4(a0 + bc0 + cx, a1 + bc1 + cy,
                                   a2 + bc2 + cx, a3 + bc3 + cy);
        }
    }

    // ---- Phase 1 tail: row wbase+48, lanes 0..15 only ----
    if (gr == 0) {
        const int r = wbase + 48;
        const float4* __restrict__ rp = lf + (tile + r) * 64;
        float ap = 0.f, a0 = 0.f, a1 = 0.f, a2 = 0.f, a3 = 0.f;
        #pragma unroll
        for (int t = 0; t < 4; ++t) {
            const float4 x = rp[o + 16 * t];
            ap += dot4(x, wp[t]);
            a0 += dot4(x, w0[t]);
            a1 += dot4(x, w1[t]);
            a2 += dot4(x, w2[t]);
            a3 += dot4(x, w3[t]);
        }
        #pragma unroll
        for (int off = 1; off <= 8; off <<= 1) {
            ap += __shfl_xor(ap, off);
            a0 += __shfl_xor(a0, off);
            a1 += __shfl_xor(a1, off);
            a2 += __shfl_xor(a2, off);
            a3 += __shfl_xor(a3, off);
        }
        if (o == 0) {
            const float lg = ap + bp;
            s_logit[r] = lg;
            presence_out[tile + r] = lg;
            const int   ix = r % GG, iy = r / GG;
            const float cx = (ix + 0.5f) / (float)GG;
            const float cy = (iy + 0.5f) / (float)GG;
            s_box[r] = make_float4(a0 + bc0 + cx, a1 + bc1 + cy,
                                   a2 + bc2 + cx, a3 + bc3 + cy);
        }
    }

    __syncthreads();
    if (wv != 0) return;

    // ---- Phase 2 (wave 0): top-K argmax over LDS logits ----
    float v[4]; int id[4];
    #pragma unroll
    for (int t = 0; t < 4; ++t) {
        const int r = lane + 64 * t;
        id[t] = r;
        v[t]  = (r < RR) ? s_logit[r] : -1e30f;
    }

    float myv = -1e30f; int myi = 0;
    for (int k = 0; k < KK; ++k) {
        float bv = v[0]; int bi = id[0];
        #pragma unroll
        for (int t = 1; t < 4; ++t)
            if (v[t] > bv || (v[t] == bv && id[t] < bi)) { bv = v[t]; bi = id[t]; }
        #pragma unroll
        for (int off = 32; off; off >>= 1) {
            const float ov = __shfl_xor(bv, off);
            const int   oi = __shfl_xor(bi, off);
            if (ov > bv || (ov == bv && oi < bi)) { bv = ov; bi = oi; }
        }
        #pragma unroll
        for (int t = 0; t < 4; ++t)
            if (id[t] == bi) v[t] = -1e30f;
        if (lane == k) { myv = bv; myi = bi; }
    }

    // ---- box fetch + NMS ----
    float x1 = 0.f, y1 = 0.f, x2 = 0.f, y2 = 0.f, area = 0.f, prob = 0.f;
    int kp = 0;
    if (lane < KK) {
        const float4 b = s_box[myi];
        x1 = b.x; y1 = b.y; x2 = b.z; y2 = b.w;
        area = fmaxf(x2 - x1, 0.f) * fmaxf(y2 - y1, 0.f);
        prob = 1.f / (1.f + expf(-myv));
        kp   = (prob > CONF_) ? 1 : 0;
    }
    for (int i = 0; i < KK; ++i) {
        const int   ki  = __shfl(kp, i);
        const float bx1 = __shfl(x1, i), by1 = __shfl(y1, i);
        const float bx2 = __shfl(x2, i), by2 = __shfl(y2, i);
        const float ai  = __shfl(area, i);
        if (lane > i && lane < KK && ki) {
            const float xx1 = fmaxf(x1, bx1), yy1 = fmaxf(y1, by1);
            const float xx2 = fminf(x2, bx2), yy2 = fminf(y2, by2);
            const float inter = fmaxf(xx2 - xx1, 0.f) * fmaxf(yy2 - yy1, 0.f);
            const float uni   = area + ai - inter;
            const float iou   = inter / fmaxf(uni, 1e-9f);
            if (iou > IOU_THR_) kp = 0;
        }
    }

    // ---- outputs ----
    if (lane < KK) {
        const size_t obase = (size_t)bc * KK + lane;
        const float  kf    = kp ? 1.f : 0.f;
        coords_out[obase * 4 + 0] = x1 * kf;
        coords_out[obase * 4 + 1] = y1 * kf;
        coords_out[obase * 4 + 2] = x2 * kf;
        coords_out[obase * 4 + 3] = y2 * kf;
        probs_out[obase] = prob * kf;
        keep_out[obase]  = kf;
    }
}

extern "C" void kernel_launch(void* const* d_in, const int* in_sizes, int n_in,
                              void* d_out, int out_size, void* d_ws, size_t ws_size,
                              hipStream_t stream) {
    const float* lf       = (const float*)d_in[0];
    const float* W_coords = (const float*)d_in[1];
    const float* b_coords = (const float*)d_in[2];
    const float* W_pres   = (const float*)d_in[3];
    const float* b_pres   = (const float*)d_in[4];

    float* out          = (float*)d_out;
    float* coords_out   = out + COORDS_OFF;
    float* probs_out    = out + PROBS_OFF;
    float* keep_out     = out + KEEP_OFF;
    float* presence_out = out + PRES_OFF;

    // One block per (b,c); 960 blocks, fully independent (single launch).
    fused_bbox_final<<<BB * CC, 256, 0, stream>>>(
        (const float4*)lf, W_coords, b_coords, W_pres, b_pres,
        coords_out, probs_out, keep_out, presence_out);
}